// Round 5
// baseline (94.676 us; speedup 1.0000x reference)
//
#include <hip/hip_runtime.h>
#include <math.h>

#define EPSBN 1e-5f

constexpr int B_ = 8, C_ = 256, N_ = 4096, IMG_ = 64;
constexpr int HEADS_ = 4, K_ = 16, VV_ = 64, M_ = 11, OC_ = 144;

typedef _Float16 half4 __attribute__((ext_vector_type(4)));
typedef float f32x4 __attribute__((ext_vector_type(4)));

// workspace layout (float offsets)
constexpr size_t O_WT   = 0;                                   // Wf16[144][256] (f16, 18432 floats used)
constexpr size_t O_BIAS = 36864;                               // [144]
constexpr size_t O_EMBT = 37120;                               // embF16[11][16][16] (f16)
constexpr size_t O_Q    = 39424;                               // QT[8][4096][64]  (pos-major!)
constexpr size_t O_KEYS = O_Q    + (size_t)B_ * 64 * N_;       // [8][16][4096]
constexpr size_t O_SM   = O_KEYS + (size_t)B_ * 16 * N_;       // [8][16][4096]
constexpr size_t O_VALS = O_SM   + (size_t)B_ * 16 * N_;       // [8][64][4096]
constexpr size_t O_VALT = O_VALS + (size_t)B_ * 64 * N_;       // [8][4096][64]
constexpr size_t O_LCP  = O_VALT + (size_t)B_ * (size_t)N_ * 64; // [8][16][16][64]
constexpr size_t O_LC   = O_LCP  + (size_t)B_ * 16 * 16 * 64;  // [8][16][64]

// ---------------- K0: fold BN into f16 weights, build f16 emb table ------
__global__ void k_prep(const float* __restrict__ Wq,
                       const float* __restrict__ qg, const float* __restrict__ qb,
                       const float* __restrict__ qm, const float* __restrict__ qv,
                       const float* __restrict__ Wk, const float* __restrict__ Wv,
                       const float* __restrict__ vg, const float* __restrict__ vb,
                       const float* __restrict__ vm, const float* __restrict__ vva,
                       const float* __restrict__ emb, float* __restrict__ ws) {
    int t = threadIdx.x, blk = blockIdx.x;
    _Float16* wf = (_Float16*)(ws + O_WT);
    int base = blk * 2304;                       // 16 blocks x 2304 = 36864
#pragma unroll
    for (int i = 0; i < 9; i++) {
        int idx = base + i * 256 + t;
        int o = idx >> 8, c = idx & 255;         // Wf16[o][c]
        float w;
        if (o < 64) {
            float s = qg[o] * rsqrtf(qv[o] + EPSBN);
            w = Wq[o * 256 + c] * s;
        } else if (o < 80) {
            w = Wk[(o - 64) * 256 + c];
        } else {
            int ov = o - 80;
            float s = vg[ov] * rsqrtf(vva[ov] + EPSBN);
            w = Wv[ov * 256 + c] * s;
        }
        wf[idx] = (_Float16)w;
    }
    if (blk == 0 && t < 144) {
        float bias;
        if (t < 64) {
            float s = qg[t] * rsqrtf(qv[t] + EPSBN);
            bias = qb[t] - qm[t] * s;
        } else if (t < 80) {
            bias = 0.f;
        } else {
            int ov = t - 80;
            float s = vg[ov] * rsqrtf(vva[ov] + EPSBN);
            bias = vb[ov] - vm[ov] * s;
        }
        ws[O_BIAS + t] = bias;
    }
    if (blk == 15) {
        // embF16[dy][dx(16, zero-pad >=11)][k(16)] = emb[k][dy][dx]
        _Float16* ef = (_Float16*)(ws + O_EMBT);
        for (int idx = t; idx < 11 * 16 * 16; idx += 256) {
            int dy = idx >> 8, dx = (idx >> 4) & 15, k = idx & 15;
            float v = (dx < 11) ? emb[k * 121 + dy * 11 + dx] : 0.f;
            ef[idx] = (_Float16)v;
        }
    }
}

// ---------------- K1: MFMA q/k/v projection ------------------------------
// C[144, Ntile=128] = W[144,256] x X[256,128] via 16x16x16 f16 MFMA.
__global__ __launch_bounds__(256) void k_proj(const float* __restrict__ x,
                                              const float* __restrict__ wsc,
                                              float* __restrict__ ws) {
    __shared__ uint WL[144 * 130];   // 74880 B
    __shared__ uint XL[128 * 130];   // 66560 B
    int b    = blockIdx.y;
    int pos0 = blockIdx.x * 128;
    int t    = threadIdx.x;

    // stage W (144*128 uints, consecutive)
    const uint* wsrc = (const uint*)(wsc + O_WT);
#pragma unroll
    for (int i = 0; i < 72; i++) {
        int u = t + i * 256;
        int o = u >> 7, cu = u & 127;
        WL[o * 130 + cu] = wsrc[u];
    }
    // stage x transposed+f16: tasks = 128 c-pairs x 32 pos-quads
    const float* xb = x + (size_t)b * C_ * N_ + pos0;
#pragma unroll
    for (int i = 0; i < 16; i++) {
        int f = t + i * 256;
        int cp = f >> 5, p4 = f & 31;
        float4 a0 = *(const float4*)(xb + (size_t)(2 * cp) * N_ + 4 * p4);
        float4 a1 = *(const float4*)(xb + (size_t)(2 * cp + 1) * N_ + 4 * p4);
        union { _Float16 h[2]; uint u; } pk;
#pragma unroll
        for (int j = 0; j < 4; j++) {
            float v0 = (j == 0) ? a0.x : (j == 1) ? a0.y : (j == 2) ? a0.z : a0.w;
            float v1 = (j == 0) ? a1.x : (j == 1) ? a1.y : (j == 2) ? a1.z : a1.w;
            pk.h[0] = (_Float16)v0; pk.h[1] = (_Float16)v1;
            XL[(4 * p4 + j) * 130 + cp] = pk.u;
        }
    }
    __syncthreads();

    int w = t >> 6, l = t & 63;
    int g = l >> 4, r = l & 15;

    f32x4 acc[9][2];
#pragma unroll
    for (int mf = 0; mf < 9; mf++)
#pragma unroll
        for (int nf = 0; nf < 2; nf++) acc[mf][nf] = (f32x4){0.f, 0.f, 0.f, 0.f};

    union u2h { uint2 u; half4 h; };
    for (int ks = 0; ks < 16; ks++) {
        int cu = 8 * ks + 2 * g;
        u2h bf0, bf1;
        bf0.u = *(const uint2*)&XL[((2 * w + 0) * 16 + r) * 130 + cu];
        bf1.u = *(const uint2*)&XL[((2 * w + 1) * 16 + r) * 130 + cu];
#pragma unroll
        for (int mf = 0; mf < 9; mf++) {
            u2h af;
            af.u = *(const uint2*)&WL[(16 * mf + r) * 130 + cu];
            acc[mf][0] = __builtin_amdgcn_mfma_f32_16x16x16f16(af.h, bf0.h, acc[mf][0], 0, 0, 0);
            acc[mf][1] = __builtin_amdgcn_mfma_f32_16x16x16f16(af.h, bf1.h, acc[mf][1], 0, 0, 0);
        }
    }

    // epilogue: D[m=16mf+4g+reg][n=pos], add bias, route outputs
#pragma unroll
    for (int mf = 0; mf < 9; mf++) {
        float4 bias4 = *(const float4*)(wsc + O_BIAS + 16 * mf + 4 * g);
        int ch0 = 16 * mf + 4 * g;
#pragma unroll
        for (int nf = 0; nf < 2; nf++) {
            int pos = pos0 + (2 * w + nf) * 16 + r;
            f32x4 a = acc[mf][nf];
            float rv0 = a[0] + bias4.x, rv1 = a[1] + bias4.y;
            float rv2 = a[2] + bias4.z, rv3 = a[3] + bias4.w;
            if (mf < 4) {
                // QT[b][pos][ch]  (pos-major, float4)
                float4 v4 = make_float4(rv0, rv1, rv2, rv3);
                *(float4*)(ws + O_Q + ((size_t)b * N_ + pos) * 64 + ch0) = v4;
            } else if (mf == 4) {
                float* kp = ws + O_KEYS + ((size_t)(b * 16 + (ch0 - 64))) * N_ + pos;
                kp[0] = rv0; kp[(size_t)N_] = rv1; kp[2 * (size_t)N_] = rv2; kp[3 * (size_t)N_] = rv3;
            } else {
                int ov = ch0 - 80;
                float* vp = ws + O_VALS + ((size_t)(b * 64 + ov)) * N_ + pos;
                vp[0] = rv0; vp[(size_t)N_] = rv1; vp[2 * (size_t)N_] = rv2; vp[3 * (size_t)N_] = rv3;
                float4 v4 = make_float4(rv0, rv1, rv2, rv3);
                *(float4*)(ws + O_VALT + ((size_t)b * N_ + pos) * 64 + ov) = v4;
            }
        }
    }
}

// ---------------- K2: row softmax over keys ------------------------------
__global__ __launch_bounds__(1024) void k_softmax(float* __restrict__ ws) {
    int row = blockIdx.x;   // b*16 + k
    const float* src = ws + O_KEYS + (size_t)row * N_;
    float*       dst = ws + O_SM   + (size_t)row * N_;
    int t = threadIdx.x;

    float4 r = *(const float4*)(src + t * 4);

    float m = fmaxf(fmaxf(r.x, r.y), fmaxf(r.z, r.w));
    for (int off = 32; off > 0; off >>= 1) m = fmaxf(m, __shfl_xor(m, off));
    __shared__ float redm[16];
    __shared__ float reds[16];
    if ((t & 63) == 0) redm[t >> 6] = m;
    __syncthreads();
    m = redm[0];
#pragma unroll
    for (int i = 1; i < 16; i++) m = fmaxf(m, redm[i]);

    r.x = expf(r.x - m); r.y = expf(r.y - m);
    r.z = expf(r.z - m); r.w = expf(r.w - m);
    float s = r.x + r.y + r.z + r.w;
    for (int off = 32; off > 0; off >>= 1) s += __shfl_xor(s, off);
    if ((t & 63) == 0) reds[t >> 6] = s;
    __syncthreads();
    s = reds[0];
#pragma unroll
    for (int i = 1; i < 16; i++) s += reds[i];
    float inv = 1.f / s;
    r.x *= inv; r.y *= inv; r.z *= inv; r.w *= inv;
    *(float4*)(dst + t * 4) = r;
}

// ---------------- K3: lam_c partials --------------------------------------
__global__ __launch_bounds__(256) void k_lamc(float* __restrict__ ws) {
    int b  = blockIdx.x >> 4;
    int ch = blockIdx.x & 15;     // n-chunk
    int n0 = ch * 256;
    __shared__ float sms[16 * 256];
    int t = threadIdx.x;
    for (int i = 0; i < 16; i++) {
        int idx = t + i * 256;
        int k = idx >> 8, n = idx & 255;
        sms[idx] = ws[O_SM + ((size_t)(b * 16 + k)) * N_ + n0 + n];
    }
    __syncthreads();

    int v  = t & 63;
    int kg = __builtin_amdgcn_readfirstlane(t >> 6);
    float acc[4] = {0.f, 0.f, 0.f, 0.f};
    const float* vt = ws + O_VALT + ((size_t)b * N_ + n0) * 64 + v;
    for (int n = 0; n < 256; n++) {
        float val = vt[(size_t)n * 64];
#pragma unroll
        for (int j = 0; j < 4; j++) acc[j] += sms[(kg * 4 + j) * 256 + n] * val;
    }
#pragma unroll
    for (int j = 0; j < 4; j++)
        ws[O_LCP + ((size_t)(b * 16 + ch) * 16 + kg * 4 + j) * 64 + v] = acc[j];
}

// ---------------- K4: reduce lam_c partials -------------------------------
__global__ void k_lcred(float* __restrict__ ws) {
    int b = blockIdx.x, t = threadIdx.x;   // 1024 threads = 16k x 64v
    float s = 0.f;
    for (int c = 0; c < 16; c++)
        s += ws[O_LCP + ((size_t)(b * 16 + c)) * 1024 + t];
    ws[O_LC + (size_t)b * 1024 + t] = s;
}

// ---------------- K5: MFMA conv + y_p + y_c -------------------------------
__global__ __launch_bounds__(256, 4) void k_out(const float* __restrict__ wsc,
                                                float* __restrict__ out) {
    __shared__ _Float16 vt[2][4][18][88];   // 25344 B
    int ytile = blockIdx.x;                 // 0..7  (8 rows each)
    int vc    = blockIdx.y;                 // 0..15 (4 v each)
    int b     = blockIdx.z;
    int y0 = ytile * 8, v0 = vc * 4;
    int t = threadIdx.x;
    int w = t >> 6, l = t & 63;
    int g = l >> 4, nb = l & 15;

    // lam_c for this lane's 4 k-slices x 4 v: lc4[i][vidx]
    float4 lc4[4];
#pragma unroll
    for (int i = 0; i < 4; i++)
        lc4[i] = *(const float4*)(wsc + O_LC + ((size_t)(b * 16 + 4 * g + i)) * 64 + v0);

    // ---- stage value tile as f16, two copies (copy1 shifted left by 1) ----
    const float* vsrc = wsc + O_VALS + (size_t)b * 64 * N_;
    for (int idx = t; idx < 2 * 4 * 18 * 88; idx += 256) {
        int cp = idx / 6336, rem = idx % 6336;
        int v = rem / 1584, rem2 = rem % 1584;
        int r = rem2 / 88, c = rem2 % 88;
        int gy = y0 - 5 + r, gx = c - 8 + cp;
        _Float16 h = (_Float16)0.f;
        if ((unsigned)gy < 64u && (unsigned)gx < 64u)
            h = (_Float16)vsrc[(size_t)(v0 + v) * N_ + gy * 64 + gx];
        vt[cp][v][r][c] = h;
    }

    // ---- preload the 11 A-fragments (emb) --------------------------------
    half4 af[11];
    const _Float16* ef = (const _Float16*)(wsc + O_EMBT);
#pragma unroll
    for (int dy = 0; dy < 11; dy++) {
#pragma unroll
        for (int i = 0; i < 4; i++)
            af[dy][i] = ef[(dy * 16 + 4 * g + i) * 16 + nb];
    }

    __syncthreads();

    const char* ldsB = (const char*)&vt[0][0][0][0];

    for (int yy2 = 0; yy2 < 2; yy2++) {
        int yy = w * 2 + yy2;               // output row within tile (0..7)
        for (int xt = 0; xt < 4; xt++) {
            int pos = (y0 + yy) * 64 + xt * 16 + nb;
            // q[h][0..3] for this lane's 4 k-slices: 4x float4 from QT
            float4 qf[4];
            const float* qsrc = wsc + O_Q + ((size_t)b * N_ + pos) * 64 + 4 * g;
#pragma unroll
            for (int h = 0; h < 4; h++)
                qf[h] = *(const float4*)(qsrc + h * 16);

            int base = xt * 16 + nb + 4 * g + 3;    // window start (array col)
            int cp = base & 1, ub = base & ~1;

            for (int vp = 0; vp < 2; vp++) {
                int vA = vp * 2, vB = vp * 2 + 1;
                f32x4 dA = {0.f, 0.f, 0.f, 0.f}, dB = {0.f, 0.f, 0.f, 0.f};
                const char* pA = ldsB + (size_t)cp * 12672 + ((vA * 18 + yy) * 88 + ub) * 2;
                const char* pB = ldsB + (size_t)cp * 12672 + ((vB * 18 + yy) * 88 + ub) * 2;
#pragma unroll
                for (int dy = 0; dy < 11; dy++) {
                    union { uint u[2]; half4 h; } bA, bB;
                    bA.u[0] = *(const uint*)(pA + dy * 176);
                    bA.u[1] = *(const uint*)(pA + dy * 176 + 4);
                    bB.u[0] = *(const uint*)(pB + dy * 176);
                    bB.u[1] = *(const uint*)(pB + dy * 176 + 4);
                    dA = __builtin_amdgcn_mfma_f32_16x16x16f16(af[dy], bA.h, dA, 0, 0, 0);
                    dB = __builtin_amdgcn_mfma_f32_16x16x16f16(af[dy], bB.h, dB, 0, 0, 0);
                }
                // + lam_c, then contract with q, butterfly-reduce over k-groups
#pragma unroll
                for (int vv = 0; vv < 2; vv++) {
                    f32x4 d = vv ? dB : dA;
                    int vidx = vp * 2 + vv;
                    float d0 = d[0] + lc4[0][vidx];
                    float d1 = d[1] + lc4[1][vidx];
                    float d2 = d[2] + lc4[2][vidx];
                    float d3 = d[3] + lc4[3][vidx];
                    float ph[4];
#pragma unroll
                    for (int h = 0; h < 4; h++) {
                        float p = qf[h][0] * d0 + qf[h][1] * d1 + qf[h][2] * d2 + qf[h][3] * d3;
                        p += __shfl_xor(p, 16);
                        p += __shfl_xor(p, 32);
                        ph[h] = p;
                    }
                    float o = (g == 0) ? ph[0] : (g == 1) ? ph[1] : (g == 2) ? ph[2] : ph[3];
                    out[((size_t)(b * 256 + g * 64 + v0 + vidx)) * N_ + pos] = o;
                }
            }
        }
    }
}

extern "C" void kernel_launch(void* const* d_in, const int* in_sizes, int n_in,
                              void* d_out, int out_size, void* d_ws, size_t ws_size,
                              hipStream_t stream) {
    const float* x   = (const float*)d_in[0];
    const float* Wq  = (const float*)d_in[1];
    const float* qg  = (const float*)d_in[2];
    const float* qb  = (const float*)d_in[3];
    const float* qm  = (const float*)d_in[4];
    const float* qv  = (const float*)d_in[5];
    const float* Wk  = (const float*)d_in[6];
    const float* Wv  = (const float*)d_in[7];
    const float* vg  = (const float*)d_in[8];
    const float* vb  = (const float*)d_in[9];
    const float* vm  = (const float*)d_in[10];
    const float* vva = (const float*)d_in[11];
    const float* emb = (const float*)d_in[12];
    float* ws  = (float*)d_ws;
    float* out = (float*)d_out;

    k_prep<<<16, 256, 0, stream>>>(Wq, qg, qb, qm, qv, Wk, Wv, vg, vb, vm, vva, emb, ws);
    k_proj<<<dim3(32, 8), 256, 0, stream>>>(x, ws, ws);
    k_softmax<<<128, 1024, 0, stream>>>(ws);
    k_lamc<<<128, 256, 0, stream>>>(ws);
    k_lcred<<<8, 1024, 0, stream>>>(ws);
    k_out<<<dim3(8, 16, 8), 256, 0, stream>>>(ws, out);
}

// Round 7
// 82.279 us; speedup vs baseline: 1.1507x; 1.1507x over previous
//
#include <hip/hip_runtime.h>
#include <math.h>

#define EPSBN 1e-5f

constexpr int B_ = 8, C_ = 256, N_ = 4096, IMG_ = 64;
constexpr int HEADS_ = 4, K_ = 16, VV_ = 64, M_ = 11, OC_ = 144;

typedef _Float16 half4 __attribute__((ext_vector_type(4)));
typedef _Float16 half8 __attribute__((ext_vector_type(8)));
typedef float f32x4 __attribute__((ext_vector_type(4)));

// workspace layout (float offsets)
constexpr size_t O_WT   = 0;                                   // Wf16[144][256] (f16)
constexpr size_t O_BIAS = 36864;                               // [144]
constexpr size_t O_EMBT = 37120;                               // embP[64][6][8] f16 (per-lane 96B rows)
constexpr size_t O_Q    = 39424;                               // QT[8][4096][64] (pos-major)
constexpr size_t O_KEYS = O_Q    + (size_t)B_ * 64 * N_;       // [8][16][4096]
constexpr size_t O_SM   = O_KEYS + (size_t)B_ * 16 * N_;       // [8][16][4096]
constexpr size_t O_VP   = O_SM   + (size_t)B_ * 16 * N_;       // f16 VP[8][64][80][88]
constexpr size_t O_VALT = O_VP   + (size_t)B_ * 64 * N_;       // [8][4096][64] f32
constexpr size_t O_LCP  = O_VALT + (size_t)B_ * (size_t)N_ * 64; // [8][16][16][64]
constexpr size_t O_LC   = O_LCP  + (size_t)B_ * 16 * 16 * 64;  // [8][16][64]

constexpr int VPROW = 88, VPPLANE = 80 * 88;                   // f16 elems

// ---------------- K0: fold BN into f16 weights, build embP table ----------
__global__ void k_prep(const float* __restrict__ Wq,
                       const float* __restrict__ qg, const float* __restrict__ qb,
                       const float* __restrict__ qm, const float* __restrict__ qv,
                       const float* __restrict__ Wk, const float* __restrict__ Wv,
                       const float* __restrict__ vg, const float* __restrict__ vb,
                       const float* __restrict__ vm, const float* __restrict__ vva,
                       const float* __restrict__ emb, float* __restrict__ ws) {
    int t = threadIdx.x, blk = blockIdx.x;
    _Float16* wf = (_Float16*)(ws + O_WT);
    int base = blk * 2304;                       // 16 blocks x 2304 = 36864
#pragma unroll
    for (int i = 0; i < 9; i++) {
        int idx = base + i * 256 + t;
        int o = idx >> 8, c = idx & 255;         // Wf16[o][c]
        float w;
        if (o < 64) {
            float s = qg[o] * rsqrtf(qv[o] + EPSBN);
            w = Wq[o * 256 + c] * s;
        } else if (o < 80) {
            w = Wk[(o - 64) * 256 + c];
        } else {
            int ov = o - 80;
            float s = vg[ov] * rsqrtf(vva[ov] + EPSBN);
            w = Wv[ov * 256 + c] * s;
        }
        wf[idx] = (_Float16)w;
    }
    if (blk == 0 && t < 144) {
        float bias;
        if (t < 64) {
            float s = qg[t] * rsqrtf(qv[t] + EPSBN);
            bias = qb[t] - qm[t] * s;
        } else if (t < 80) {
            bias = 0.f;
        } else {
            int ov = t - 80;
            float s = vg[ov] * rsqrtf(vva[ov] + EPSBN);
            bias = vb[ov] - vm[ov] * s;
        }
        ws[O_BIAS + t] = bias;
    }
    if (blk == 15) {
        // embP[l][dp][j] = emb[k=l&15][dy=2dp+(j>>2)][dx=4*(l>>4)+(j&3)], 0-padded
        _Float16* ef = (_Float16*)(ws + O_EMBT);
        for (int idx = t; idx < 64 * 48; idx += 256) {
            int l = idx / 48, rem = idx % 48;
            int dp = rem >> 3, j = rem & 7;
            int k = l & 15, g = l >> 4;
            int dy = 2 * dp + (j >> 2), dx = 4 * g + (j & 3);
            float v = (dy < 11 && dx < 11) ? emb[k * 121 + dy * 11 + dx] : 0.f;
            ef[idx] = (_Float16)v;
        }
    }
}

// ---------------- K0b: zero the padded VP plane ---------------------------
__global__ void k_zero(float* __restrict__ ws) {
    size_t i = (size_t)blockIdx.x * 256 + threadIdx.x;   // 1760*256 = 450560 f4
    f32x4 z = {0.f, 0.f, 0.f, 0.f};
    *(f32x4*)(ws + O_VP + i * 4) = z;
}

// ---------------- K1: MFMA q/k/v projection ------------------------------
__global__ __launch_bounds__(256) void k_proj(const float* __restrict__ x,
                                              const float* __restrict__ wsc,
                                              float* __restrict__ ws) {
    __shared__ uint WL[144 * 130];   // 74880 B
    __shared__ uint XL[128 * 130];   // 66560 B
    int b    = blockIdx.y;
    int pos0 = blockIdx.x * 128;
    int t    = threadIdx.x;

    const uint* wsrc = (const uint*)(wsc + O_WT);
#pragma unroll
    for (int i = 0; i < 72; i++) {
        int u = t + i * 256;
        int o = u >> 7, cu = u & 127;
        WL[o * 130 + cu] = wsrc[u];
    }
    const float* xb = x + (size_t)b * C_ * N_ + pos0;
#pragma unroll
    for (int i = 0; i < 16; i++) {
        int f = t + i * 256;
        int cp = f >> 5, p4 = f & 31;
        float4 a0 = *(const float4*)(xb + (size_t)(2 * cp) * N_ + 4 * p4);
        float4 a1 = *(const float4*)(xb + (size_t)(2 * cp + 1) * N_ + 4 * p4);
        union { _Float16 h[2]; uint u; } pk;
#pragma unroll
        for (int j = 0; j < 4; j++) {
            float v0 = (j == 0) ? a0.x : (j == 1) ? a0.y : (j == 2) ? a0.z : a0.w;
            float v1 = (j == 0) ? a1.x : (j == 1) ? a1.y : (j == 2) ? a1.z : a1.w;
            pk.h[0] = (_Float16)v0; pk.h[1] = (_Float16)v1;
            XL[(4 * p4 + j) * 130 + cp] = pk.u;
        }
    }
    __syncthreads();

    int w = t >> 6, l = t & 63;
    int g = l >> 4, r = l & 15;

    f32x4 acc[9][2];
#pragma unroll
    for (int mf = 0; mf < 9; mf++)
#pragma unroll
        for (int nf = 0; nf < 2; nf++) acc[mf][nf] = (f32x4){0.f, 0.f, 0.f, 0.f};

    union u2h { uint2 u; half4 h; };
    for (int ks = 0; ks < 16; ks++) {
        int cu = 8 * ks + 2 * g;
        u2h bf0, bf1;
        bf0.u = *(const uint2*)&XL[((2 * w + 0) * 16 + r) * 130 + cu];
        bf1.u = *(const uint2*)&XL[((2 * w + 1) * 16 + r) * 130 + cu];
#pragma unroll
        for (int mf = 0; mf < 9; mf++) {
            u2h af;
            af.u = *(const uint2*)&WL[(16 * mf + r) * 130 + cu];
            acc[mf][0] = __builtin_amdgcn_mfma_f32_16x16x16f16(af.h, bf0.h, acc[mf][0], 0, 0, 0);
            acc[mf][1] = __builtin_amdgcn_mfma_f32_16x16x16f16(af.h, bf1.h, acc[mf][1], 0, 0, 0);
        }
    }

#pragma unroll
    for (int mf = 0; mf < 9; mf++) {
        float4 bias4 = *(const float4*)(wsc + O_BIAS + 16 * mf + 4 * g);
        int ch0 = 16 * mf + 4 * g;
#pragma unroll
        for (int nf = 0; nf < 2; nf++) {
            int pos = pos0 + (2 * w + nf) * 16 + r;
            f32x4 a = acc[mf][nf];
            float rv0 = a[0] + bias4.x, rv1 = a[1] + bias4.y;
            float rv2 = a[2] + bias4.z, rv3 = a[3] + bias4.w;
            if (mf < 4) {
                float4 v4 = make_float4(rv0, rv1, rv2, rv3);
                *(float4*)(ws + O_Q + ((size_t)b * N_ + pos) * 64 + ch0) = v4;
            } else if (mf == 4) {
                float* kp = ws + O_KEYS + ((size_t)(b * 16 + (ch0 - 64))) * N_ + pos;
                kp[0] = rv0; kp[(size_t)N_] = rv1; kp[2 * (size_t)N_] = rv2; kp[3 * (size_t)N_] = rv3;
            } else {
                int ov = ch0 - 80;
                int y = pos >> 6, xx = pos & 63;
                _Float16* vp = (_Float16*)(ws + O_VP) +
                               ((size_t)(b * 64 + ov)) * VPPLANE + (size_t)(y + 8) * VPROW + (xx + 8);
                vp[0] = (_Float16)rv0; vp[VPPLANE] = (_Float16)rv1;
                vp[2 * VPPLANE] = (_Float16)rv2; vp[3 * VPPLANE] = (_Float16)rv3;
                float4 v4 = make_float4(rv0, rv1, rv2, rv3);
                *(float4*)(ws + O_VALT + ((size_t)b * N_ + pos) * 64 + ov) = v4;
            }
        }
    }
}

// ---------------- K2: row softmax over keys ------------------------------
__global__ __launch_bounds__(1024) void k_softmax(float* __restrict__ ws) {
    int row = blockIdx.x;   // b*16 + k
    const float* src = ws + O_KEYS + (size_t)row * N_;
    float*       dst = ws + O_SM   + (size_t)row * N_;
    int t = threadIdx.x;

    float4 r = *(const float4*)(src + t * 4);

    float m = fmaxf(fmaxf(r.x, r.y), fmaxf(r.z, r.w));
    for (int off = 32; off > 0; off >>= 1) m = fmaxf(m, __shfl_xor(m, off));
    __shared__ float redm[16];
    __shared__ float reds[16];
    if ((t & 63) == 0) redm[t >> 6] = m;
    __syncthreads();
    m = redm[0];
#pragma unroll
    for (int i = 1; i < 16; i++) m = fmaxf(m, redm[i]);

    r.x = expf(r.x - m); r.y = expf(r.y - m);
    r.z = expf(r.z - m); r.w = expf(r.w - m);
    float s = r.x + r.y + r.z + r.w;
    for (int off = 32; off > 0; off >>= 1) s += __shfl_xor(s, off);
    if ((t & 63) == 0) reds[t >> 6] = s;
    __syncthreads();
    s = reds[0];
#pragma unroll
    for (int i = 1; i < 16; i++) s += reds[i];
    float inv = 1.f / s;
    r.x *= inv; r.y *= inv; r.z *= inv; r.w *= inv;
    *(float4*)(dst + t * 4) = r;
}

// ---------------- K3: lam_c partials --------------------------------------
__global__ __launch_bounds__(256) void k_lamc(float* __restrict__ ws) {
    int b  = blockIdx.x >> 4;
    int ch = blockIdx.x & 15;     // n-chunk
    int n0 = ch * 256;
    __shared__ float sms[16 * 256];
    int t = threadIdx.x;
    for (int i = 0; i < 16; i++) {
        int idx = t + i * 256;
        int k = idx >> 8, n = idx & 255;
        sms[idx] = ws[O_SM + ((size_t)(b * 16 + k)) * N_ + n0 + n];
    }
    __syncthreads();

    int v  = t & 63;
    int kg = __builtin_amdgcn_readfirstlane(t >> 6);
    float acc[4] = {0.f, 0.f, 0.f, 0.f};
    const float* vt = ws + O_VALT + ((size_t)b * N_ + n0) * 64 + v;
    for (int n = 0; n < 256; n++) {
        float val = vt[(size_t)n * 64];
#pragma unroll
        for (int j = 0; j < 4; j++) acc[j] += sms[(kg * 4 + j) * 256 + n] * val;
    }
#pragma unroll
    for (int j = 0; j < 4; j++)
        ws[O_LCP + ((size_t)(b * 16 + ch) * 16 + kg * 4 + j) * 64 + v] = acc[j];
}

// ---------------- K4: reduce lam_c partials -------------------------------
__global__ void k_lcred(float* __restrict__ ws) {
    int b = blockIdx.x, t = threadIdx.x;   // 1024 threads = 16k x 64v
    float s = 0.f;
    for (int c = 0; c < 16; c++)
        s += ws[O_LCP + ((size_t)(b * 16 + c)) * 1024 + t];
    ws[O_LC + (size_t)b * 1024 + t] = s;
}

// ---------------- K5: MFMA(K=32) conv + y_p + y_c -------------------------
// 2-copy shifted f16 LDS tile; B-frag = 2x(uint pair) (rows dy, dy+1);
// A = embP (6 dwordx4/lane); rotated-q 3-shuffle head reduction.
// NOTE: stage 19 rows (not 18) — the dy=11 zero-tap reads LDS row 18; it
// must be real (zero-padded VP) data, not uninitialized LDS (NaN risk).
__global__ __launch_bounds__(256, 4) void k_out(const float* __restrict__ wsc,
                                                float* __restrict__ out) {
    __shared__ ushort vt[2][4][19][84];      // 25536 B
    int ytile = blockIdx.x;                  // 0..7 (8 rows each)
    int vc    = blockIdx.y;                  // 0..15 (4 v each)
    int b     = blockIdx.z;
    int y0 = ytile * 8, v0 = vc * 4;
    int t = threadIdx.x;
    int w = t >> 6, l = t & 63;
    int g = l >> 4, nb = l & 15;

    // lam_c for this lane's 4 k-slices x 4 v
    float4 lc4[4];
#pragma unroll
    for (int i = 0; i < 4; i++)
        lc4[i] = *(const float4*)(wsc + O_LC + ((size_t)(b * 16 + 4 * g + i)) * 64 + v0);

    // A-fragments: embP, per-lane 96B contiguous
    union afu_t { uint4 u; half8 h; } af[6];
    {
        const uint4* ap = (const uint4*)((const _Float16*)(wsc + O_EMBT) + (size_t)l * 48);
#pragma unroll
        for (int dp = 0; dp < 6; dp++) af[dp].u = ap[dp];
    }

    // ---- stage 2-copy shifted value tile from padded VP (19 rows!) -------
    const ushort* vpb = (const ushort*)(wsc + O_VP) + (size_t)(b * 64 + v0) * VPPLANE;
    for (int T = t; T < 1596; T += 256) {
        int v = T / 399, rem = T % 399;       // 399 = 19 rows * 21 quads
        int r = rem / 21, qd = rem % 21;
        const ushort* src = vpb + (size_t)v * VPPLANE + (size_t)(y0 + 3 + r) * VPROW + 4 * qd;
        uint2 u01 = *(const uint2*)src;
        uint2 u23 = *(const uint2*)(src + 4);
        *(uint2*)&vt[0][v][r][4 * qd] = u01;
        uint lo = (u01.x >> 16) | (u01.y << 16);
        uint hi = (u01.y >> 16) | (u23.x << 16);
        *(uint2*)&vt[1][v][r][4 * qd] = make_uint2(lo, hi);
    }
    __syncthreads();

    const uint* vtu = (const uint*)&vt[0][0][0][0];

    for (int yy2 = 0; yy2 < 2; yy2++) {
        int yy = w * 2 + yy2;                // output row within tile (0..7)
        for (int xt = 0; xt < 4; xt++) {
            int X = xt * 16 + nb;
            int pos = (y0 + yy) * 64 + X;

            // rotated q: qf[j] = q[h = g^j][4g..4g+3]
            float4 qf[4];
            const float* qsrc = wsc + O_Q + ((size_t)b * N_ + pos) * 64;
#pragma unroll
            for (int j = 0; j < 4; j++)
                qf[j] = *(const float4*)(qsrc + ((g ^ j) * 16 + 4 * g));

            int wcol = X + 4 * g + 3;
            int cpp  = wcol & 1;
            int j0u  = (wcol - cpp) >> 1;    // uint col index (even f16 col / 2)

#pragma unroll
            for (int v = 0; v < 4; v++) {
                int bu = ((cpp * 4 + v) * 19 + yy) * 42 + j0u;
                f32x4 acc = {0.f, 0.f, 0.f, 0.f};
#pragma unroll
                for (int dp = 0; dp < 6; dp++) {
                    union { uint u[4]; half8 h; } bb;
                    int r0 = bu + (2 * dp) * 42;
                    bb.u[0] = vtu[r0];      bb.u[1] = vtu[r0 + 1];
                    bb.u[2] = vtu[r0 + 42]; bb.u[3] = vtu[r0 + 43];
                    acc = __builtin_amdgcn_mfma_f32_16x16x32_f16(af[dp].h, bb.h, acc, 0, 0, 0);
                }
                float d0 = acc[0] + lc4[0][v];
                float d1 = acc[1] + lc4[1][v];
                float d2 = acc[2] + lc4[2][v];
                float d3 = acc[3] + lc4[3][v];
                float p0 = qf[0].x * d0 + qf[0].y * d1 + qf[0].z * d2 + qf[0].w * d3;
                float p1 = qf[1].x * d0 + qf[1].y * d1 + qf[1].z * d2 + qf[1].w * d3;
                float p2 = qf[2].x * d0 + qf[2].y * d1 + qf[2].z * d2 + qf[2].w * d3;
                float p3 = qf[3].x * d0 + qf[3].y * d1 + qf[3].z * d2 + qf[3].w * d3;
                float sa = p0 + __shfl_xor(p1, 16);
                float sb = p2 + __shfl_xor(p3, 16);
                float o  = sa + __shfl_xor(sb, 32);
                out[((size_t)(b * 256 + g * 64 + v0 + v)) * N_ + pos] = o;
            }
        }
    }
}

extern "C" void kernel_launch(void* const* d_in, const int* in_sizes, int n_in,
                              void* d_out, int out_size, void* d_ws, size_t ws_size,
                              hipStream_t stream) {
    const float* x   = (const float*)d_in[0];
    const float* Wq  = (const float*)d_in[1];
    const float* qg  = (const float*)d_in[2];
    const float* qb  = (const float*)d_in[3];
    const float* qm  = (const float*)d_in[4];
    const float* qv  = (const float*)d_in[5];
    const float* Wk  = (const float*)d_in[6];
    const float* Wv  = (const float*)d_in[7];
    const float* vg  = (const float*)d_in[8];
    const float* vb  = (const float*)d_in[9];
    const float* vm  = (const float*)d_in[10];
    const float* vva = (const float*)d_in[11];
    const float* emb = (const float*)d_in[12];
    float* ws  = (float*)d_ws;
    float* out = (float*)d_out;

    k_prep<<<16, 256, 0, stream>>>(Wq, qg, qb, qm, qv, Wk, Wv, vg, vb, vm, vva, emb, ws);
    k_zero<<<1760, 256, 0, stream>>>(ws);
    k_proj<<<dim3(32, 8), 256, 0, stream>>>(x, ws, ws);
    k_softmax<<<128, 1024, 0, stream>>>(ws);
    k_lamc<<<128, 256, 0, stream>>>(ws);
    k_lcred<<<8, 1024, 0, stream>>>(ws);
    k_out<<<dim3(8, 16, 8), 256, 0, stream>>>(ws, out);
}

// Round 11
// 71.759 us; speedup vs baseline: 1.3194x; 1.1466x over previous
//
#include <hip/hip_runtime.h>
#include <math.h>

#define EPSBN 1e-5f

constexpr int B_ = 8, C_ = 256, N_ = 4096, IMG_ = 64;
constexpr int HEADS_ = 4, K_ = 16, VV_ = 64, M_ = 11, OC_ = 144;

typedef _Float16 half4 __attribute__((ext_vector_type(4)));
typedef _Float16 half8 __attribute__((ext_vector_type(8)));
typedef __fp16 fp16x2 __attribute__((ext_vector_type(2)));
typedef float f32x4 __attribute__((ext_vector_type(4)));

// workspace layout (float offsets) — audited r10/r11:
//   Wf16[144][256] f16 = 18432 fl ; emb = 64*48 f16 = 1536 fl (slot 6144)
//   QF = 8*16*4096 uint2 = 1048576 fl ; KEYS/SM = 524288 fl each
//   VP = 8*64*80*88 f16 = 1802240 fl ; VT16 = 1048576 fl
//   LCP = 131072 fl ; LC = 8192 fl
constexpr size_t O_WT   = 0;
constexpr size_t O_BIAS = 18432;
constexpr size_t O_EMBT = 18688;
constexpr size_t O_Q    = 24832;
constexpr size_t O_KEYS = O_Q    + 1048576;   // 1073408
constexpr size_t O_SM   = O_KEYS + 524288;    // 1597696
constexpr size_t O_VP   = O_SM   + 524288;    // 2121984
constexpr size_t O_VT16 = O_VP   + 1802240;   // 3924224
constexpr size_t O_LCP  = O_VT16 + 1048576;   // 4972800
constexpr size_t O_LC   = O_LCP  + 131072;    // 5103872

constexpr int VPROW = 88, VPPLANE = 80 * 88;   // f16 elems

// ---------------- K0: fold BN into f16 weights, build embP table ----------
__global__ void k_prep(const float* __restrict__ Wq,
                       const float* __restrict__ qg, const float* __restrict__ qb,
                       const float* __restrict__ qm, const float* __restrict__ qv,
                       const float* __restrict__ Wk, const float* __restrict__ Wv,
                       const float* __restrict__ vg, const float* __restrict__ vb,
                       const float* __restrict__ vm, const float* __restrict__ vva,
                       const float* __restrict__ emb, float* __restrict__ ws) {
    int t = threadIdx.x, blk = blockIdx.x;
    _Float16* wf = (_Float16*)(ws + O_WT);
    int base = blk * 2304;                       // 16 blocks x 2304 = 36864
#pragma unroll
    for (int i = 0; i < 9; i++) {
        int idx = base + i * 256 + t;
        int o = idx >> 8, c = idx & 255;         // Wf16[o][c]
        float w;
        if (o < 64) {
            float s = qg[o] * rsqrtf(qv[o] + EPSBN);
            w = Wq[o * 256 + c] * s;
        } else if (o < 80) {
            w = Wk[(o - 64) * 256 + c];
        } else {
            int ov = o - 80;
            float s = vg[ov] * rsqrtf(vva[ov] + EPSBN);
            w = Wv[ov * 256 + c] * s;
        }
        wf[idx] = (_Float16)w;
    }
    if (blk == 0 && t < 144) {
        float bias;
        if (t < 64) {
            float s = qg[t] * rsqrtf(qv[t] + EPSBN);
            bias = qb[t] - qm[t] * s;
        } else if (t < 80) {
            bias = 0.f;
        } else {
            int ov = t - 80;
            float s = vg[ov] * rsqrtf(vva[ov] + EPSBN);
            bias = vb[ov] - vm[ov] * s;
        }
        ws[O_BIAS + t] = bias;
    }
    if (blk == 15) {
        // embP[l][dp][j] = emb[k=l&15][dy=2dp+(j>>2)][dx=4*(l>>4)+(j&3)]
        // LANE-INDEPENDENT slot->tap map (cpq shift was invalid: MFMA pairs
        // A from lane(m) with B from lane(n), m != n in general).
        _Float16* ef = (_Float16*)(ws + O_EMBT);
        for (int idx = t; idx < 64 * 48; idx += 256) {
            int l = idx / 48, rem = idx % 48;
            int dp = rem >> 3, j = rem & 7;
            int k = l & 15, g = l >> 4;
            int dy = 2 * dp + (j >> 2);
            int dx = 4 * g + (j & 3);
            float v = (dy < 11 && dx < 11) ? emb[k * 121 + dy * 11 + dx] : 0.f;
            ef[idx] = (_Float16)v;
        }
    }
}

// ---------------- K0b: zero the padded VP plane (1802240 fl) --------------
__global__ void k_zero(float* __restrict__ ws) {
    size_t i = (size_t)blockIdx.x * 256 + threadIdx.x;   // 1760*256 = 450560 f4
    f32x4 z = {0.f, 0.f, 0.f, 0.f};
    *(f32x4*)(ws + O_VP + i * 4) = z;
}

// ---------------- K1: MFMA q/k/v projection (K-split, 64-pos tiles) -------
__global__ __launch_bounds__(256) void k_proj(const float* __restrict__ x,
                                              const float* __restrict__ wsc,
                                              float* __restrict__ ws) {
    __shared__ uint WL[144 * 68];   // 39168 B
    __shared__ uint XL[64 * 68];    // 17408 B
    int b    = blockIdx.y;
    int pos0 = blockIdx.x * 64;
    int t    = threadIdx.x;
    int w = t >> 6, l = t & 63;
    int g = l >> 4, r = l & 15;

    f32x4 acc[9];
#pragma unroll
    for (int mf = 0; mf < 9; mf++) acc[mf] = (f32x4){0.f, 0.f, 0.f, 0.f};

    const uint* wsrc = (const uint*)(wsc + O_WT);
    const float* xb = x + (size_t)b * C_ * N_ + pos0;
    union u2h { uint2 u; half4 h; };

    for (int kh = 0; kh < 2; kh++) {
        if (kh) __syncthreads();    // WAR: everyone done reading half 0
#pragma unroll
        for (int i = 0; i < 9; i++) {
            int idx = t + i * 256;
            int o = idx >> 4, c4 = idx & 15;
            uint4 wv = *(const uint4*)(wsrc + o * 128 + kh * 64 + c4 * 4);
            *(uint4*)&WL[o * 68 + c4 * 4] = wv;
        }
#pragma unroll
        for (int i = 0; i < 4; i++) {
            int idx = t + i * 256;
            int cl = idx >> 4, p4 = idx & 15;
            float4 a0 = *(const float4*)(xb + (size_t)(2 * (64 * kh + cl)) * N_ + 4 * p4);
            float4 a1 = *(const float4*)(xb + (size_t)(2 * (64 * kh + cl) + 1) * N_ + 4 * p4);
            union { _Float16 h[2]; uint u; } pk;
#pragma unroll
            for (int j = 0; j < 4; j++) {
                float v0 = (j == 0) ? a0.x : (j == 1) ? a0.y : (j == 2) ? a0.z : a0.w;
                float v1 = (j == 0) ? a1.x : (j == 1) ? a1.y : (j == 2) ? a1.z : a1.w;
                pk.h[0] = (_Float16)v0; pk.h[1] = (_Float16)v1;
                XL[(4 * p4 + j) * 68 + cl] = pk.u;
            }
        }
        __syncthreads();

        for (int ks = 0; ks < 8; ks++) {
            int cu = 8 * ks + 2 * g;
            u2h bf;
            bf.u = *(const uint2*)&XL[(w * 16 + r) * 68 + cu];
#pragma unroll
            for (int mf = 0; mf < 9; mf++) {
                u2h af;
                af.u = *(const uint2*)&WL[(16 * mf + r) * 68 + cu];
                acc[mf] = __builtin_amdgcn_mfma_f32_16x16x16f16(af.h, bf.h, acc[mf], 0, 0, 0);
            }
        }
    }

    // epilogue: D[m=16mf+4g+reg][n=pos], pos = pos0 + 16w + r
    int pos = pos0 + w * 16 + r;
#pragma unroll
    for (int mf = 0; mf < 9; mf++) {
        float4 bias4 = *(const float4*)(wsc + O_BIAS + 16 * mf + 4 * g);
        f32x4 a = acc[mf];
        float rv0 = a[0] + bias4.x, rv1 = a[1] + bias4.y;
        float rv2 = a[2] + bias4.z, rv3 = a[3] + bias4.w;
        if (mf < 4) {
            union { fp16x2 h[2]; uint2 u; } pk;
            pk.h[0] = __builtin_amdgcn_cvt_pkrtz(rv0, rv1);
            pk.h[1] = __builtin_amdgcn_cvt_pkrtz(rv2, rv3);
            ((uint2*)(ws + O_Q))[((size_t)(b * 16 + 4 * mf + g)) * N_ + pos] = pk.u;
        } else if (mf == 4) {
            int ch0 = 16 * mf + 4 * g;
            float* kp = ws + O_KEYS + ((size_t)(b * 16 + (ch0 - 64))) * N_ + pos;
            kp[0] = rv0; kp[(size_t)N_] = rv1; kp[2 * (size_t)N_] = rv2; kp[3 * (size_t)N_] = rv3;
        } else {
            int ov = 16 * mf + 4 * g - 80;
            int y = pos >> 6, xx = pos & 63;
            _Float16* vp = (_Float16*)(ws + O_VP) +
                           ((size_t)(b * 64 + ov)) * VPPLANE + (size_t)(y + 8) * VPROW + (xx + 8);
            vp[0] = (_Float16)rv0; vp[VPPLANE] = (_Float16)rv1;
            vp[2 * VPPLANE] = (_Float16)rv2; vp[3 * VPPLANE] = (_Float16)rv3;
            union { fp16x2 h[2]; uint2 u; } pk;
            pk.h[0] = __builtin_amdgcn_cvt_pkrtz(rv0, rv1);
            pk.h[1] = __builtin_amdgcn_cvt_pkrtz(rv2, rv3);
            ((uint2*)(ws + O_VT16))[((size_t)b * N_ + pos) * 16 + 4 * (mf - 5) + g] = pk.u;
        }
    }
}

// ---------------- K2: row softmax over keys ------------------------------
__global__ __launch_bounds__(1024) void k_softmax(float* __restrict__ ws) {
    int row = blockIdx.x;   // b*16 + k
    const float* src = ws + O_KEYS + (size_t)row * N_;
    float*       dst = ws + O_SM   + (size_t)row * N_;
    int t = threadIdx.x;

    float4 r = *(const float4*)(src + t * 4);

    float m = fmaxf(fmaxf(r.x, r.y), fmaxf(r.z, r.w));
    for (int off = 32; off > 0; off >>= 1) m = fmaxf(m, __shfl_xor(m, off));
    __shared__ float redm[16];
    __shared__ float reds[16];
    if ((t & 63) == 0) redm[t >> 6] = m;
    __syncthreads();
    m = redm[0];
#pragma unroll
    for (int i = 1; i < 16; i++) m = fmaxf(m, redm[i]);

    r.x = expf(r.x - m); r.y = expf(r.y - m);
    r.z = expf(r.z - m); r.w = expf(r.w - m);
    float s = r.x + r.y + r.z + r.w;
    for (int off = 32; off > 0; off >>= 1) s += __shfl_xor(s, off);
    if ((t & 63) == 0) reds[t >> 6] = s;
    __syncthreads();
    s = reds[0];
#pragma unroll
    for (int i = 1; i < 16; i++) s += reds[i];
    float inv = 1.f / s;
    r.x *= inv; r.y *= inv; r.z *= inv; r.w *= inv;
    *(float4*)(dst + t * 4) = r;
}

// ---------------- K3: lam_c partials (VT16 f16 reads) ---------------------
__global__ __launch_bounds__(256) void k_lamc(float* __restrict__ ws) {
    int b  = blockIdx.x >> 4;
    int ch = blockIdx.x & 15;     // n-chunk
    int n0 = ch * 256;
    __shared__ float sms[16 * 256];
    int t = threadIdx.x;
    for (int i = 0; i < 16; i++) {
        int idx = t + i * 256;
        int k = idx >> 8, n = idx & 255;
        sms[idx] = ws[O_SM + ((size_t)(b * 16 + k)) * N_ + n0 + n];
    }
    __syncthreads();

    int v  = t & 63;
    int kg = __builtin_amdgcn_readfirstlane(t >> 6);
    float acc[4] = {0.f, 0.f, 0.f, 0.f};
    const _Float16* vt = (const _Float16*)(ws + O_VT16) + ((size_t)b * N_ + n0) * 64 + v;
    for (int n = 0; n < 256; n++) {
        float val = (float)vt[(size_t)n * 64];
#pragma unroll
        for (int j = 0; j < 4; j++) acc[j] += sms[(kg * 4 + j) * 256 + n] * val;
    }
#pragma unroll
    for (int j = 0; j < 4; j++)
        ws[O_LCP + ((size_t)(b * 16 + ch) * 16 + kg * 4 + j) * 64 + v] = acc[j];
}

// ---------------- K4: reduce lam_c partials -------------------------------
__global__ void k_lcred(float* __restrict__ ws) {
    int b = blockIdx.x, t = threadIdx.x;   // 1024 threads = 16k x 64v
    float s = 0.f;
    for (int c = 0; c < 16; c++)
        s += ws[O_LCP + ((size_t)(b * 16 + c)) * 1024 + t];
    ws[O_LC + (size_t)b * 1024 + t] = s;
}

// ---------------- K5: MFMA(K=32) conv + y_p + y_c (v5) --------------------
// Dual-copy (normal + shift-1) LDS tile: the per-COLUMN copy select cp is
// valid (all B contributions to column n come from lanes with l&15==n).
// A = lane-independent embP (6 dwordx4). Register row-window win[13] per
// (xt,v) reused across both yy rows and all 6 dp. f16 q + fdot2 epilogue.
__global__ __launch_bounds__(256, 4) void k_out(const float* __restrict__ wsc,
                                                float* __restrict__ out) {
    __shared__ ushort vt[2][4][19][84];      // 25536 B
    int ytile = blockIdx.x;                  // 0..7 (8 rows each)
    int vc    = blockIdx.y;                  // 0..15 (4 v each)
    int b     = blockIdx.z;
    int y0 = ytile * 8, v0 = vc * 4;
    int t = threadIdx.x;
    int w = t >> 6, l = t & 63;
    int g = l >> 4, nb = l & 15;

    // lam_c f32 for this lane's 4 k-slices x 4 v
    float4 lc4[4];
#pragma unroll
    for (int i = 0; i < 4; i++)
        lc4[i] = *(const float4*)(wsc + O_LC + ((size_t)(b * 16 + 4 * g + i)) * 64 + v0);

    // A-fragments: embP, per-lane 96B contiguous
    union AF { uint4 u; half8 h; } af[6];
    {
        const uint4* ap = (const uint4*)((const _Float16*)(wsc + O_EMBT) + (size_t)l * 48);
#pragma unroll
        for (int dp = 0; dp < 6; dp++) af[dp].u = ap[dp];
    }

    // stage dual-copy value tile (19 rows incl. zero-pad row 18)
    const ushort* vpb = (const ushort*)(wsc + O_VP) + (size_t)(b * 64 + v0) * VPPLANE;
    for (int T = t; T < 1596; T += 256) {
        int v = T / 399, rem = T % 399;       // 399 = 19 rows * 21 quads
        int r = rem / 21, qd = rem % 21;
        const ushort* src = vpb + (size_t)v * VPPLANE + (size_t)(y0 + 3 + r) * VPROW + 4 * qd;
        uint2 u01 = *(const uint2*)src;
        uint2 u23 = *(const uint2*)(src + 4);
        *(uint2*)&vt[0][v][r][4 * qd] = u01;
        uint lo = (u01.x >> 16) | (u01.y << 16);
        uint hi = (u01.y >> 16) | (u23.x << 16);
        *(uint2*)&vt[1][v][r][4 * qd] = make_uint2(lo, hi);
    }
    __syncthreads();

    const uint* vtu = (const uint*)&vt[0][0][0][0];
    const uint2* qfp = (const uint2*)(wsc + O_Q);

#pragma unroll
    for (int xt = 0; xt < 4; xt++) {
        int X = xt * 16 + nb;
        // q f16: qh[yy2][j] = q[h=g^j][4g..4g+3] at pos(yy2)
        union QH { uint2 u; fp16x2 h[2]; } qh[2][4];
#pragma unroll
        for (int yy2 = 0; yy2 < 2; yy2++) {
            int pos = (y0 + 2 * w + yy2) * 64 + X;
#pragma unroll
            for (int j = 0; j < 4; j++)
                qh[yy2][j].u = qfp[((size_t)(b * 16 + 4 * (g ^ j) + g)) * N_ + pos];
        }
        int wcol = X + 4 * g + 3;            // window start (orig cols)
        int cp   = wcol & 1;
        int j0u  = (wcol - cp) >> 1;         // uint col in copy cp

#pragma unroll
        for (int v = 0; v < 4; v++) {
            int bwin = ((cp * 4 + v) * 19 + 2 * w) * 42 + j0u;
            uint2 win[13];
#pragma unroll
            for (int i = 0; i < 13; i++) {
                win[i].x = vtu[bwin + 42 * i];
                win[i].y = vtu[bwin + 42 * i + 1];
            }

#pragma unroll
            for (int yy2 = 0; yy2 < 2; yy2++) {
                f32x4 acc = {0.f, 0.f, 0.f, 0.f};
#pragma unroll
                for (int dp = 0; dp < 6; dp++) {
                    union { uint u[4]; half8 h; } bb;
                    bb.u[0] = win[yy2 + 2 * dp].x;
                    bb.u[1] = win[yy2 + 2 * dp].y;
                    bb.u[2] = win[yy2 + 2 * dp + 1].x;
                    bb.u[3] = win[yy2 + 2 * dp + 1].y;
                    acc = __builtin_amdgcn_mfma_f32_16x16x32_f16(af[dp].h, bb.h, acc, 0, 0, 0);
                }
                float d0 = acc[0] + lc4[0][v];
                float d1 = acc[1] + lc4[1][v];
                float d2 = acc[2] + lc4[2][v];
                float d3 = acc[3] + lc4[3][v];
                fp16x2 dlo = __builtin_amdgcn_cvt_pkrtz(d0, d1);
                fp16x2 dhi = __builtin_amdgcn_cvt_pkrtz(d2, d3);
                float ph[4];
#pragma unroll
                for (int j = 0; j < 4; j++)
                    ph[j] = __builtin_amdgcn_fdot2(qh[yy2][j].h[0], dlo,
                            __builtin_amdgcn_fdot2(qh[yy2][j].h[1], dhi, 0.f, false), false);
                float sa = ph[0] + __shfl_xor(ph[1], 16);
                float sb = ph[2] + __shfl_xor(ph[3], 16);
                float o  = sa + __shfl_xor(sb, 32);
                int pos = (y0 + 2 * w + yy2) * 64 + X;
                out[((size_t)(b * 256 + g * 64 + v0 + v)) * N_ + pos] = o;
            }
        }
    }
}

extern "C" void kernel_launch(void* const* d_in, const int* in_sizes, int n_in,
                              void* d_out, int out_size, void* d_ws, size_t ws_size,
                              hipStream_t stream) {
    const float* x   = (const float*)d_in[0];
    const float* Wq  = (const float*)d_in[1];
    const float* qg  = (const float*)d_in[2];
    const float* qb  = (const float*)d_in[3];
    const float* qm  = (const float*)d_in[4];
    const float* qv  = (const float*)d_in[5];
    const float* Wk  = (const float*)d_in[6];
    const float* Wv  = (const float*)d_in[7];
    const float* vg  = (const float*)d_in[8];
    const float* vb  = (const float*)d_in[9];
    const float* vm  = (const float*)d_in[10];
    const float* vva = (const float*)d_in[11];
    const float* emb = (const float*)d_in[12];
    float* ws  = (float*)d_ws;
    float* out = (float*)d_out;

    k_prep<<<16, 256, 0, stream>>>(Wq, qg, qb, qm, qv, Wk, Wv, vg, vb, vm, vva, emb, ws);
    k_zero<<<1760, 256, 0, stream>>>(ws);
    k_proj<<<dim3(64, 8), 256, 0, stream>>>(x, ws, ws);
    k_softmax<<<128, 1024, 0, stream>>>(ws);
    k_lamc<<<128, 256, 0, stream>>>(ws);
    k_lcred<<<8, 1024, 0, stream>>>(ws);
    k_out<<<dim3(8, 16, 8), 256, 0, stream>>>(ws, out);
}

// Round 12
// 61.587 us; speedup vs baseline: 1.5373x; 1.1652x over previous
//
#include <hip/hip_runtime.h>
#include <math.h>

#define EPSBN 1e-5f

constexpr int B_ = 8, C_ = 256, N_ = 4096, IMG_ = 64;
constexpr int HEADS_ = 4, K_ = 16, VV_ = 64, M_ = 11, OC_ = 144;

typedef _Float16 half4 __attribute__((ext_vector_type(4)));
typedef _Float16 half8 __attribute__((ext_vector_type(8)));
typedef __fp16 fp16x2 __attribute__((ext_vector_type(2)));
typedef float f32x4 __attribute__((ext_vector_type(4)));

// workspace layout (float offsets) — r12: SM & VT16 deleted, SINV added
constexpr size_t O_WT   = 0;                  // Wf16[144][256] f16 = 18432 fl
constexpr size_t O_BIAS = 18432;              // [144] f32
constexpr size_t O_EMBT = 18688;              // embP 64*48 f16 (slot to 24832)
constexpr size_t O_Q    = 24832;              // QF[8][16cq][4096] uint2 = 1048576 fl
constexpr size_t O_KEYS = O_Q    + 1048576;   // 1073408: [8][16][4096] f32
constexpr size_t O_SINV = O_KEYS + 524288;    // 1597696: [128] inv-denominators
constexpr size_t O_VP   = 1597952;            // f16 VP[8][64][80][88] = 1802240 fl
constexpr size_t O_LCP  = O_VP   + 1802240;   // 3400192: [8][32][16][64] f32 = 262144
constexpr size_t O_LC   = O_LCP  + 262144;    // 3662336: [8][16][64] f32

constexpr int VPROW = 88, VPPLANE = 80 * 88;  // f16 elems

// ---------------- K0: fold BN weights + embP + zero VP (merged) -----------
__global__ void k_prep(const float* __restrict__ Wq,
                       const float* __restrict__ qg, const float* __restrict__ qb,
                       const float* __restrict__ qm, const float* __restrict__ qv,
                       const float* __restrict__ Wk, const float* __restrict__ Wv,
                       const float* __restrict__ vg, const float* __restrict__ vb,
                       const float* __restrict__ vm, const float* __restrict__ vva,
                       const float* __restrict__ emb, float* __restrict__ ws) {
    int t = threadIdx.x, blk = blockIdx.x;
    if (blk >= 16) {   // zero VP: 1760 blocks x 256 f4 = 450560 f4 = 1802240 fl
        size_t i = (size_t)(blk - 16) * 256 + t;
        f32x4 z = {0.f, 0.f, 0.f, 0.f};
        *(f32x4*)(ws + O_VP + i * 4) = z;
        return;
    }
    _Float16* wf = (_Float16*)(ws + O_WT);
    int base = blk * 2304;                       // 16 blocks x 2304 = 36864
#pragma unroll
    for (int i = 0; i < 9; i++) {
        int idx = base + i * 256 + t;
        int o = idx >> 8, c = idx & 255;         // Wf16[o][c]
        float w;
        if (o < 64) {
            float s = qg[o] * rsqrtf(qv[o] + EPSBN);
            w = Wq[o * 256 + c] * s;
        } else if (o < 80) {
            w = Wk[(o - 64) * 256 + c];
        } else {
            int ov = o - 80;
            float s = vg[ov] * rsqrtf(vva[ov] + EPSBN);
            w = Wv[ov * 256 + c] * s;
        }
        wf[idx] = (_Float16)w;
    }
    if (blk == 0 && t < 144) {
        float bias;
        if (t < 64) {
            float s = qg[t] * rsqrtf(qv[t] + EPSBN);
            bias = qb[t] - qm[t] * s;
        } else if (t < 80) {
            bias = 0.f;
        } else {
            int ov = t - 80;
            float s = vg[ov] * rsqrtf(vva[ov] + EPSBN);
            bias = vb[ov] - vm[ov] * s;
        }
        ws[O_BIAS + t] = bias;
    }
    if (blk == 15) {
        // embP[l][dp][j] = emb[k=l&15][dy=2dp+(j>>2)][dx=4*(l>>4)+(j&3)]
        _Float16* ef = (_Float16*)(ws + O_EMBT);
        for (int idx = t; idx < 64 * 48; idx += 256) {
            int l = idx / 48, rem = idx % 48;
            int dp = rem >> 3, j = rem & 7;
            int k = l & 15, g = l >> 4;
            int dy = 2 * dp + (j >> 2);
            int dx = 4 * g + (j & 3);
            float v = (dy < 11 && dx < 11) ? emb[k * 121 + dy * 11 + dx] : 0.f;
            ef[idx] = (_Float16)v;
        }
    }
}

// ---------------- K1: MFMA q/k/v projection (K-split, 64-pos tiles) -------
__global__ __launch_bounds__(256) void k_proj(const float* __restrict__ x,
                                              const float* __restrict__ wsc,
                                              float* __restrict__ ws) {
    __shared__ uint WL[144 * 68];   // 39168 B
    __shared__ uint XL[64 * 68];    // 17408 B
    int b    = blockIdx.y;
    int pos0 = blockIdx.x * 64;
    int t    = threadIdx.x;
    int w = t >> 6, l = t & 63;
    int g = l >> 4, r = l & 15;

    f32x4 acc[9];
#pragma unroll
    for (int mf = 0; mf < 9; mf++) acc[mf] = (f32x4){0.f, 0.f, 0.f, 0.f};

    const uint* wsrc = (const uint*)(wsc + O_WT);
    const float* xb = x + (size_t)b * C_ * N_ + pos0;
    union u2h { uint2 u; half4 h; };

    for (int kh = 0; kh < 2; kh++) {
        if (kh) __syncthreads();    // WAR: everyone done reading half 0
#pragma unroll
        for (int i = 0; i < 9; i++) {
            int idx = t + i * 256;
            int o = idx >> 4, c4 = idx & 15;
            uint4 wv = *(const uint4*)(wsrc + o * 128 + kh * 64 + c4 * 4);
            *(uint4*)&WL[o * 68 + c4 * 4] = wv;
        }
#pragma unroll
        for (int i = 0; i < 4; i++) {
            int idx = t + i * 256;
            int cl = idx >> 4, p4 = idx & 15;
            float4 a0 = *(const float4*)(xb + (size_t)(2 * (64 * kh + cl)) * N_ + 4 * p4);
            float4 a1 = *(const float4*)(xb + (size_t)(2 * (64 * kh + cl) + 1) * N_ + 4 * p4);
            union { _Float16 h[2]; uint u; } pk;
#pragma unroll
            for (int j = 0; j < 4; j++) {
                float v0 = (j == 0) ? a0.x : (j == 1) ? a0.y : (j == 2) ? a0.z : a0.w;
                float v1 = (j == 0) ? a1.x : (j == 1) ? a1.y : (j == 2) ? a1.z : a1.w;
                pk.h[0] = (_Float16)v0; pk.h[1] = (_Float16)v1;
                XL[(4 * p4 + j) * 68 + cl] = pk.u;
            }
        }
        __syncthreads();

        for (int ks = 0; ks < 8; ks++) {
            int cu = 8 * ks + 2 * g;
            u2h bf;
            bf.u = *(const uint2*)&XL[(w * 16 + r) * 68 + cu];
#pragma unroll
            for (int mf = 0; mf < 9; mf++) {
                u2h af;
                af.u = *(const uint2*)&WL[(16 * mf + r) * 68 + cu];
                acc[mf] = __builtin_amdgcn_mfma_f32_16x16x16f16(af.h, bf.h, acc[mf], 0, 0, 0);
            }
        }
    }

    // epilogue: D[m=16mf+4g+reg][n=pos], pos = pos0 + 16w + r
    int pos = pos0 + w * 16 + r;
#pragma unroll
    for (int mf = 0; mf < 9; mf++) {
        float4 bias4 = *(const float4*)(wsc + O_BIAS + 16 * mf + 4 * g);
        f32x4 a = acc[mf];
        float rv0 = a[0] + bias4.x, rv1 = a[1] + bias4.y;
        float rv2 = a[2] + bias4.z, rv3 = a[3] + bias4.w;
        if (mf < 4) {
            union { fp16x2 h[2]; uint2 u; } pk;
            pk.h[0] = __builtin_amdgcn_cvt_pkrtz(rv0, rv1);
            pk.h[1] = __builtin_amdgcn_cvt_pkrtz(rv2, rv3);
            ((uint2*)(ws + O_Q))[((size_t)(b * 16 + 4 * mf + g)) * N_ + pos] = pk.u;
        } else if (mf == 4) {
            int ch0 = 16 * mf + 4 * g;
            float* kp = ws + O_KEYS + ((size_t)(b * 16 + (ch0 - 64))) * N_ + pos;
            kp[0] = rv0; kp[(size_t)N_] = rv1; kp[2 * (size_t)N_] = rv2; kp[3 * (size_t)N_] = rv3;
        } else {
            int ov = 16 * mf + 4 * g - 80;
            int y = pos >> 6, xx = pos & 63;
            _Float16* vp = (_Float16*)(ws + O_VP) +
                           ((size_t)(b * 64 + ov)) * VPPLANE + (size_t)(y + 8) * VPROW + (xx + 8);
            vp[0] = (_Float16)rv0; vp[VPPLANE] = (_Float16)rv1;
            vp[2 * VPPLANE] = (_Float16)rv2; vp[3 * VPPLANE] = (_Float16)rv3;
        }
    }
}

// ---------------- K2: softmax denominator (no max-sub; keys ~ N(0,1)) -----
__global__ __launch_bounds__(256) void k_ssum(float* __restrict__ ws) {
    int row = blockIdx.x;   // b*16 + k
    const float* src = ws + O_KEYS + (size_t)row * N_;
    int t = threadIdx.x;
    float s = 0.f;
#pragma unroll
    for (int i = 0; i < 4; i++) {
        float4 r = *(const float4*)(src + i * 1024 + t * 4);
        s += expf(r.x) + expf(r.y) + expf(r.z) + expf(r.w);
    }
    for (int off = 32; off > 0; off >>= 1) s += __shfl_xor(s, off);
    __shared__ float reds[4];
    if ((t & 63) == 0) reds[t >> 6] = s;
    __syncthreads();
    if (t == 0)
        ws[O_SINV + row] = 1.f / (reds[0] + reds[1] + reds[2] + reds[3]);
}

// ---------------- K3: lam_c partials (fused exp; VP reads) ----------------
// Block = (b, 128-pos chunk = 2 image rows). ek[16][128] staged with
// exp(k)*inv_s applied; contraction reads VP directly (b128 ek reads).
__global__ __launch_bounds__(256) void k_lamc(float* __restrict__ ws) {
    int b  = blockIdx.x >> 5;
    int ch = blockIdx.x & 31;
    int n0 = ch * 128;
    int y0r = n0 >> 6;            // first of 2 image rows
    __shared__ float ek[16 * 128];   // 8 KB
    int t = threadIdx.x;
#pragma unroll
    for (int i = 0; i < 2; i++) {
        int f4 = t + i * 256;         // 512 float4s = 16k x 32 quads
        int k = f4 >> 5, nq = f4 & 31;
        float4 kv = *(const float4*)(ws + O_KEYS + ((size_t)(b * 16 + k)) * N_ + n0 + 4 * nq);
        float is = ws[O_SINV + b * 16 + k];
        float4 e;
        e.x = expf(kv.x) * is; e.y = expf(kv.y) * is;
        e.z = expf(kv.z) * is; e.w = expf(kv.w) * is;
        *(float4*)&ek[k * 128 + 4 * nq] = e;
    }
    __syncthreads();

    int v  = t & 63;
    int kg = __builtin_amdgcn_readfirstlane(t >> 6);
    float acc[4] = {0.f, 0.f, 0.f, 0.f};
    const _Float16* vp = (const _Float16*)(ws + O_VP) +
                         (size_t)(b * 64 + v) * VPPLANE + (size_t)(y0r + 8) * VPROW + 8;
#pragma unroll
    for (int r = 0; r < 2; r++) {
        union U4 { uint4 q; _Float16 h[8]; } u[8];
#pragma unroll
        for (int iu = 0; iu < 8; iu++)
            u[iu].q = *(const uint4*)(vp + (size_t)r * VPROW + 8 * iu);
#pragma unroll
        for (int xq = 0; xq < 16; xq++) {
            float4 e0 = *(const float4*)&ek[(kg * 4 + 0) * 128 + r * 64 + 4 * xq];
            float4 e1 = *(const float4*)&ek[(kg * 4 + 1) * 128 + r * 64 + 4 * xq];
            float4 e2 = *(const float4*)&ek[(kg * 4 + 2) * 128 + r * 64 + 4 * xq];
            float4 e3 = *(const float4*)&ek[(kg * 4 + 3) * 128 + r * 64 + 4 * xq];
            float v0 = (float)u[xq >> 1].h[(xq & 1) * 4 + 0];
            float v1 = (float)u[xq >> 1].h[(xq & 1) * 4 + 1];
            float v2 = (float)u[xq >> 1].h[(xq & 1) * 4 + 2];
            float v3 = (float)u[xq >> 1].h[(xq & 1) * 4 + 3];
            acc[0] += e0.x * v0 + e0.y * v1 + e0.z * v2 + e0.w * v3;
            acc[1] += e1.x * v0 + e1.y * v1 + e1.z * v2 + e1.w * v3;
            acc[2] += e2.x * v0 + e2.y * v1 + e2.z * v2 + e2.w * v3;
            acc[3] += e3.x * v0 + e3.y * v1 + e3.z * v2 + e3.w * v3;
        }
    }
#pragma unroll
    for (int j = 0; j < 4; j++)
        ws[O_LCP + ((size_t)(b * 32 + ch) * 16 + kg * 4 + j) * 64 + v] = acc[j];
}

// ---------------- K4: reduce lam_c partials (32 chunks) -------------------
__global__ void k_lcred(float* __restrict__ ws) {
    int b = blockIdx.x, t = threadIdx.x;   // 1024 threads = 16k x 64v
    float s = 0.f;
    for (int c = 0; c < 32; c++)
        s += ws[O_LCP + ((size_t)(b * 32 + c)) * 1024 + t];
    ws[O_LC + (size_t)b * 1024 + t] = s;
}

// ---------------- K5: MFMA(K=32) conv + y_p + y_c (v5, unchanged) ---------
__global__ __launch_bounds__(256, 4) void k_out(const float* __restrict__ wsc,
                                                float* __restrict__ out) {
    __shared__ ushort vt[2][4][19][84];      // 25536 B
    int ytile = blockIdx.x;                  // 0..7 (8 rows each)
    int vc    = blockIdx.y;                  // 0..15 (4 v each)
    int b     = blockIdx.z;
    int y0 = ytile * 8, v0 = vc * 4;
    int t = threadIdx.x;
    int w = t >> 6, l = t & 63;
    int g = l >> 4, nb = l & 15;

    float4 lc4[4];
#pragma unroll
    for (int i = 0; i < 4; i++)
        lc4[i] = *(const float4*)(wsc + O_LC + ((size_t)(b * 16 + 4 * g + i)) * 64 + v0);

    union AF { uint4 u; half8 h; } af[6];
    {
        const uint4* ap = (const uint4*)((const _Float16*)(wsc + O_EMBT) + (size_t)l * 48);
#pragma unroll
        for (int dp = 0; dp < 6; dp++) af[dp].u = ap[dp];
    }

    const ushort* vpb = (const ushort*)(wsc + O_VP) + (size_t)(b * 64 + v0) * VPPLANE;
    for (int T = t; T < 1596; T += 256) {
        int v = T / 399, rem = T % 399;       // 399 = 19 rows * 21 quads
        int r = rem / 21, qd = rem % 21;
        const ushort* src = vpb + (size_t)v * VPPLANE + (size_t)(y0 + 3 + r) * VPROW + 4 * qd;
        uint2 u01 = *(const uint2*)src;
        uint2 u23 = *(const uint2*)(src + 4);
        *(uint2*)&vt[0][v][r][4 * qd] = u01;
        uint lo = (u01.x >> 16) | (u01.y << 16);
        uint hi = (u01.y >> 16) | (u23.x << 16);
        *(uint2*)&vt[1][v][r][4 * qd] = make_uint2(lo, hi);
    }
    __syncthreads();

    const uint* vtu = (const uint*)&vt[0][0][0][0];
    const uint2* qfp = (const uint2*)(wsc + O_Q);

#pragma unroll
    for (int xt = 0; xt < 4; xt++) {
        int X = xt * 16 + nb;
        union QH { uint2 u; fp16x2 h[2]; } qh[2][4];
#pragma unroll
        for (int yy2 = 0; yy2 < 2; yy2++) {
            int pos = (y0 + 2 * w + yy2) * 64 + X;
#pragma unroll
            for (int j = 0; j < 4; j++)
                qh[yy2][j].u = qfp[((size_t)(b * 16 + 4 * (g ^ j) + g)) * N_ + pos];
        }
        int wcol = X + 4 * g + 3;
        int cp   = wcol & 1;
        int j0u  = (wcol - cp) >> 1;

#pragma unroll
        for (int v = 0; v < 4; v++) {
            int bwin = ((cp * 4 + v) * 19 + 2 * w) * 42 + j0u;
            uint2 win[13];
#pragma unroll
            for (int i = 0; i < 13; i++) {
                win[i].x = vtu[bwin + 42 * i];
                win[i].y = vtu[bwin + 42 * i + 1];
            }

#pragma unroll
            for (int yy2 = 0; yy2 < 2; yy2++) {
                f32x4 acc = {0.f, 0.f, 0.f, 0.f};
#pragma unroll
                for (int dp = 0; dp < 6; dp++) {
                    union { uint u[4]; half8 h; } bb;
                    bb.u[0] = win[yy2 + 2 * dp].x;
                    bb.u[1] = win[yy2 + 2 * dp].y;
                    bb.u[2] = win[yy2 + 2 * dp + 1].x;
                    bb.u[3] = win[yy2 + 2 * dp + 1].y;
                    acc = __builtin_amdgcn_mfma_f32_16x16x32_f16(af[dp].h, bb.h, acc, 0, 0, 0);
                }
                float d0 = acc[0] + lc4[0][v];
                float d1 = acc[1] + lc4[1][v];
                float d2 = acc[2] + lc4[2][v];
                float d3 = acc[3] + lc4[3][v];
                fp16x2 dlo = __builtin_amdgcn_cvt_pkrtz(d0, d1);
                fp16x2 dhi = __builtin_amdgcn_cvt_pkrtz(d2, d3);
                float ph[4];
#pragma unroll
                for (int j = 0; j < 4; j++)
                    ph[j] = __builtin_amdgcn_fdot2(qh[yy2][j].h[0], dlo,
                            __builtin_amdgcn_fdot2(qh[yy2][j].h[1], dhi, 0.f, false), false);
                float sa = ph[0] + __shfl_xor(ph[1], 16);
                float sb = ph[2] + __shfl_xor(ph[3], 16);
                float o  = sa + __shfl_xor(sb, 32);
                int pos = (y0 + 2 * w + yy2) * 64 + X;
                out[((size_t)(b * 256 + g * 64 + v0 + v)) * N_ + pos] = o;
            }
        }
    }
}

extern "C" void kernel_launch(void* const* d_in, const int* in_sizes, int n_in,
                              void* d_out, int out_size, void* d_ws, size_t ws_size,
                              hipStream_t stream) {
    const float* x   = (const float*)d_in[0];
    const float* Wq  = (const float*)d_in[1];
    const float* qg  = (const float*)d_in[2];
    const float* qb  = (const float*)d_in[3];
    const float* qm  = (const float*)d_in[4];
    const float* qv  = (const float*)d_in[5];
    const float* Wk  = (const float*)d_in[6];
    const float* Wv  = (const float*)d_in[7];
    const float* vg  = (const float*)d_in[8];
    const float* vb  = (const float*)d_in[9];
    const float* vm  = (const float*)d_in[10];
    const float* vva = (const float*)d_in[11];
    const float* emb = (const float*)d_in[12];
    float* ws  = (float*)d_ws;
    float* out = (float*)d_out;

    k_prep<<<1776, 256, 0, stream>>>(Wq, qg, qb, qm, qv, Wk, Wv, vg, vb, vm, vva, emb, ws);
    k_proj<<<dim3(64, 8), 256, 0, stream>>>(x, ws, ws);
    k_ssum<<<128, 256, 0, stream>>>(ws);
    k_lamc<<<256, 256, 0, stream>>>(ws);
    k_lcred<<<8, 1024, 0, stream>>>(ws);
    k_out<<<dim3(8, 16, 8), 256, 0, stream>>>(ws, out);
}